// Round 6
// baseline (53.101 us; speedup 1.0000x reference)
//
#include <hip/hip_runtime.h>
#include <float.h>

typedef __attribute__((ext_vector_type(8))) _Float16 f16x8;
typedef __attribute__((ext_vector_type(4))) _Float16 f16x4;
typedef __attribute__((ext_vector_type(4))) float f32x4;

#define WIN 128
#define SEQ 4096
#define DH 64
#define KSTR 72       // K LDS row stride (elems)
#define VSTR 260      // V^T row stride (elems): 520 B/row, dword%32=2 -> uniform b128 reads
#define PC 40         // P chunk row stride (32 keys + 8 pad)
#define VOFF 36864                    // V region byte offset
#define POFF (VOFF + DH * VSTR * 2)   // 70144: P region (8 waves x 16 q x 40 x 2B = 10240)
// total LDS = 80384 B -> 2 blocks/CU
#define L2B_OVER 0.41524101186092156f  // log2(10000)/32

__launch_bounds__(512, 4)
__global__ void lattn_kernel(const float* __restrict__ q,
                             const float* __restrict__ k,
                             const float* __restrict__ v,
                             float* __restrict__ out) {
  __shared__ __align__(16) char smem[POFF + 8 * 16 * PC * 2];
  _Float16* ksm = (_Float16*)smem;            // [256 keys][72]
  _Float16* vsm = (_Float16*)(smem + VOFF);   // [64 d][260] transposed
  _Float16* psm = (_Float16*)(smem + POFF);   // 8 waves x [16 q][40]

  const int bid  = blockIdx.x;
  const int lbid = (bid & 7) * 128 + (bid >> 3);  // bijective XCD swizzle (1024 = 8*128)
  const int bh   = lbid >> 5;
  const int win  = lbid & 31;
  const int tid  = threadIdx.x;
  const int wv   = tid >> 6;
  const int lane = tid & 63;
  const int c    = lane & 15;
  const int g    = lane >> 4;

  const long kbase = (long)win * WIN - WIN;   // global row of key 0
  const float* kb = k + (size_t)bh * SEQ * DH;
  const float* vb = v + (size_t)bh * SEQ * DH;

  // ================= cluster ALL staging loads up front =================
  // Pad rows (win==0,row<128) clamp to row 0; value is dead (masked to -inf, P=0).

  // K loads: row = c + 16*(hi>>1), p = g + 4*(hi&1), hi = it*8 + wv
  float4 klo[4], khi[4];
  #pragma unroll
  for (int it = 0; it < 4; ++it) {
    int hi  = it * 8 + wv;
    int row = c + 16 * (hi >> 1);
    int p   = g + 4 * (hi & 1);
    long grow = kbase + row; grow = grow < 0 ? 0 : grow;
    const float4* src = (const float4*)(kb + grow * DH);
    klo[it] = src[p];
    khi[it] = src[p + 8];
  }

  // V loads: key-quad kq = g + 4*(it*8+wv), d-quad dq = c; 4 consecutive key rows
  float4 vr[2][4];
  #pragma unroll
  for (int it = 0; it < 2; ++it) {
    int kq = g + 4 * (it * 8 + wv);
    #pragma unroll
    for (int i = 0; i < 4; ++i) {
      long grow = kbase + 4 * kq + i; grow = grow < 0 ? 0 : grow;
      vr[it][i] = *(const float4*)(vb + grow * DH + 4 * c);
    }
  }

  // Q loads: this wave's row qrow, d-slices 8g and 8g+32
  const int qrow = 16 * wv + c;
  const float* qp = q + ((size_t)bh * SEQ + (size_t)win * WIN + qrow) * DH;
  const float4 x0 = *(const float4*)(qp + 8 * g);
  const float4 x1 = *(const float4*)(qp + 8 * g + 4);
  const float4 y0 = *(const float4*)(qp + 8 * g + 32);
  const float4 y1 = *(const float4*)(qp + 8 * g + 36);

  // ================= process K: rope -> ksm =================
  #pragma unroll
  for (int it = 0; it < 4; ++it) {
    int hi  = it * 8 + wv;
    int row = c + 16 * (hi >> 1);
    int p   = g + 4 * (hi & 1);
    float pos = (float)row;
    f16x4 rl, rh;
    #pragma unroll
    for (int j = 0; j < 4; ++j) {
      float sn, cs;
      __sincosf(pos * exp2f(-(float)(4 * p + j) * L2B_OVER), &sn, &cs);
      float x = ((const float*)&klo[it])[j];
      float y = ((const float*)&khi[it])[j];
      rl[j] = (_Float16)(x * cs - y * sn);
      rh[j] = (_Float16)(y * cs + x * sn);
    }
    *(f16x4*)(&ksm[row * KSTR + 4 * p])      = rl;
    *(f16x4*)(&ksm[row * KSTR + 4 * p + 32]) = rh;
  }

  // ================= process V: 4x4 transpose -> vsm (b64 stores) =================
  #pragma unroll
  for (int it = 0; it < 2; ++it) {
    int kq = g + 4 * (it * 8 + wv);
    #pragma unroll
    for (int j = 0; j < 4; ++j) {
      f16x4 w;
      #pragma unroll
      for (int i = 0; i < 4; ++i) w[i] = (_Float16)(((const float*)&vr[it][i])[j]);
      *(f16x4*)(&vsm[(4 * c + j) * VSTR + 4 * kq]) = w;
    }
  }

  // ================= process Q: rope -> B-fragments (regs) =================
  f16x8 qf0, qf1;
  {
    float pos = (float)(128 + qrow);
    #pragma unroll
    for (int j = 0; j < 4; ++j) {
      float sn, cs;
      __sincosf(pos * exp2f(-(float)(8 * g + j) * L2B_OVER), &sn, &cs);
      float xa = ((const float*)&x0)[j], ya = ((const float*)&y0)[j];
      qf0[j]     = (_Float16)((xa * cs - ya * sn) * 0.125f);
      qf1[j]     = (_Float16)((ya * cs + xa * sn) * 0.125f);
      __sincosf(pos * exp2f(-(float)(8 * g + 4 + j) * L2B_OVER), &sn, &cs);
      float xb = ((const float*)&x1)[j], yb = ((const float*)&y1)[j];
      qf0[4 + j] = (_Float16)((xb * cs - yb * sn) * 0.125f);
      qf1[4 + j] = (_Float16)((yb * cs + xb * sn) * 0.125f);
    }
  }

  __syncthreads();  // the ONLY block barrier

  // ---- QK^T (swapped: A=K -> S^T). key = 16*mt + 4*g + r, query = c ----
  f32x4 acc[16];
  #pragma unroll
  for (int mt = 0; mt < 16; ++mt) acc[mt] = (f32x4){0.f, 0.f, 0.f, 0.f};

  #pragma unroll
  for (int mt = 0; mt < 16; ++mt) {
    f16x8 kf0 = *(const f16x8*)(&ksm[(16 * mt + c) * KSTR + 8 * g]);
    f16x8 kf1 = *(const f16x8*)(&ksm[(16 * mt + c) * KSTR + 32 + 8 * g]);
    acc[mt] = __builtin_amdgcn_mfma_f32_16x16x32_f16(kf0, qf0, acc[mt], 0, 0, 0);
    acc[mt] = __builtin_amdgcn_mfma_f32_16x16x32_f16(kf1, qf1, acc[mt], 0, 0, 0);
  }

  // ---- masked softmax over keys ----
  const int qi   = qrow;
  const int kmin = (win == 0) ? 128 : 0;
  float m = -FLT_MAX;
  #pragma unroll
  for (int mt = 0; mt < 16; ++mt) {
    #pragma unroll
    for (int r = 0; r < 4; ++r) {
      int j = 16 * mt + 4 * g + r;
      bool ok = (j <= qi + 128) && (j >= kmin);
      float s = ok ? acc[mt][r] : -FLT_MAX;
      acc[mt][r] = s;
      m = fmaxf(m, s);
    }
  }
  m = fmaxf(m, __shfl_xor(m, 16));
  m = fmaxf(m, __shfl_xor(m, 32));

  float sm = 0.f;
  #pragma unroll
  for (int mt = 0; mt < 16; ++mt) {
    #pragma unroll
    for (int r = 0; r < 4; ++r) {
      float p = __expf(acc[mt][r] - m);
      acc[mt][r] = p;
      sm += p;
    }
  }
  sm += __shfl_xor(sm, 16);
  sm += __shfl_xor(sm, 32);
  const float rinv = 1.0f / sm;

  // ---- PV as O^T = V^T * P^T: A = V^T (vsm), B = P^T (psm read [q][key]) ----
  // No explicit waits: per-wave psm tile, DS ops complete in order within a wave;
  // compiler inserts counted lgkmcnt for register availability.
  f32x4 oacc[4];
  #pragma unroll
  for (int nt = 0; nt < 4; ++nt) oacc[nt] = (f32x4){0.f, 0.f, 0.f, 0.f};

  _Float16* pw = psm + wv * 16 * PC;

  #pragma unroll
  for (int ks = 0; ks < 8; ++ks) {
    #pragma unroll
    for (int t = 0; t < 2; ++t) {
      int mt = 2 * ks + t;
      f16x4 pv4;
      #pragma unroll
      for (int r = 0; r < 4; ++r) pv4[r] = (_Float16)(acc[mt][r] * rinv);
      *(f16x4*)(&pw[c * PC + 16 * t + 4 * g]) = pv4;  // psm[q=c][key_in_chunk]
    }
    f16x8 pf = *(const f16x8*)(&pw[c * PC + 8 * g]);  // B = P^T: lane holds P[q=c][k=8g..]
    #pragma unroll
    for (int nt = 0; nt < 4; ++nt) {
      f16x8 vf = *(const f16x8*)(&vsm[(16 * nt + c) * VSTR + 32 * ks + 8 * g]);  // A = V^T
      oacc[nt] = __builtin_amdgcn_mfma_f32_16x16x32_f16(vf, pf, oacc[nt], 0, 0, 0);
    }
  }

  // ---- write O^T layout: lane (c,g) holds O[q=qrow][d=16nt+4g+r] -> float4 ----
  float* ob = out + ((size_t)bh * SEQ + (size_t)win * WIN + qrow) * DH;
  #pragma unroll
  for (int nt = 0; nt < 4; ++nt) {
    float4 o4 = {oacc[nt][0], oacc[nt][1], oacc[nt][2], oacc[nt][3]};
    *(float4*)(ob + 16 * nt + 4 * g) = o4;
  }
}

extern "C" void kernel_launch(void* const* d_in, const int* in_sizes, int n_in,
                              void* d_out, int out_size, void* d_ws, size_t ws_size,
                              hipStream_t stream) {
  const float* q = (const float*)d_in[0];
  const float* k = (const float*)d_in[1];
  const float* v = (const float*)d_in[2];
  float* out = (float*)d_out;
  dim3 grid(32 * 32);
  lattn_kernel<<<grid, 512, 0, stream>>>(q, k, v, out);
}

// Round 7
// 44.039 us; speedup vs baseline: 1.2058x; 1.2058x over previous
//
#include <hip/hip_runtime.h>
#include <float.h>

typedef __attribute__((ext_vector_type(8))) _Float16 f16x8;
typedef __attribute__((ext_vector_type(4))) _Float16 f16x4;
typedef __attribute__((ext_vector_type(4))) float f32x4;

#define WIN 128
#define SEQ 4096
#define DH 64
#define KSTR 72     // K LDS row stride (elems)
#define VSTR 264    // V^T LDS row stride (256 keys + 8 pad)
#define PSTR 136    // P LDS row stride (128 keys + 8 pad)
#define VOFF 36864  // byte offset of V region
// log2(10000)/32
#define L2B_OVER 0.41524101186092156f

// ---------- rope table: tbl[pos*32+f] = (cos, sin)(pos * 10000^(-f/32)) ----------
__global__ void rope_tbl_kernel(float* __restrict__ t) {
  int i = blockIdx.x * 256 + threadIdx.x;   // 0..8191 = pos*32 + f
  int pos = i >> 5, f = i & 31;
  float inv = exp2f(-(float)f * L2B_OVER);
  float s, c;
  sincosf((float)pos * inv, &s, &c);
  t[2 * i]     = c;
  t[2 * i + 1] = s;
}

// LDS: 36,864 (K, later aliased by P = 34,816) + 33,792 (V^T) = 70,656 -> 2 blocks/CU
__launch_bounds__(512, 4)
__global__ void lattn_kernel(const float* __restrict__ q,
                             const float* __restrict__ k,
                             const float* __restrict__ v,
                             const float* __restrict__ tbl,
                             float* __restrict__ out) {
  __shared__ __align__(16) char smem[70656];
  _Float16* ksm = (_Float16*)smem;           // [256 keys][72]
  _Float16* psm = (_Float16*)smem;           // aliased after 2nd barrier: 8 waves x [16 q][136]
  _Float16* vsm = (_Float16*)(smem + VOFF);  // [64 d][264 keys] transposed

  const int bid  = blockIdx.x;
  const int lbid = (bid & 7) * 128 + (bid >> 3);  // bijective XCD swizzle (1024 = 8*128)
  const int bh   = lbid >> 5;
  const int win  = lbid & 31;
  const int tid  = threadIdx.x;
  const int wv   = tid >> 6;
  const int lane = tid & 63;
  const int c    = lane & 15;
  const int g    = lane >> 4;

  const long kbase = (long)win * WIN - WIN;   // global row of key 0
  const float* kb = k + (size_t)bh * SEQ * DH;
  const float* vb = v + (size_t)bh * SEQ * DH;

  // ================= cluster the HBM staging loads =================
  // Pad rows (win==0,row<128) clamp to row 0; value is dead (masked to -inf, P=0).

  // K loads: row = c + 16*(hi>>1), p = g + 4*(hi&1), hi = it*8 + wv
  float4 klo[4], khi[4];
  #pragma unroll
  for (int it = 0; it < 4; ++it) {
    int hi  = it * 8 + wv;
    int row = c + 16 * (hi >> 1);
    int p   = g + 4 * (hi & 1);
    long grow = kbase + row; grow = grow < 0 ? 0 : grow;
    const float4* src = (const float4*)(kb + grow * DH);
    klo[it] = src[p];
    khi[it] = src[p + 8];
  }

  // V loads: key-quad kq = g + 4*(it*8+wv), d-quad = c; 4 consecutive key rows
  float4 vr[2][4];
  #pragma unroll
  for (int it = 0; it < 2; ++it) {
    int kq = g + 4 * (it * 8 + wv);
    #pragma unroll
    for (int i = 0; i < 4; ++i) {
      long grow = kbase + 4 * kq + i; grow = grow < 0 ? 0 : grow;
      vr[it][i] = *(const float4*)(vb + grow * DH + 4 * c);
    }
  }

  // Q loads
  const int qrow = 16 * wv + c;
  const float* qp = q + ((size_t)bh * SEQ + (size_t)win * WIN + qrow) * DH;
  const float4 x0 = *(const float4*)(qp + 8 * g);
  const float4 x1 = *(const float4*)(qp + 8 * g + 4);
  const float4 y0 = *(const float4*)(qp + 8 * g + 32);
  const float4 y1 = *(const float4*)(qp + 8 * g + 36);

  // ================= K: rope via table -> ksm =================
  #pragma unroll
  for (int it = 0; it < 4; ++it) {
    int hi  = it * 8 + wv;
    int row = c + 16 * (hi >> 1);
    int p   = g + 4 * (hi & 1);
    const float4* tb = (const float4*)(tbl + 2 * (row * 32 + 4 * p));
    float tt[8];
    *(float4*)(tt)     = tb[0];
    *(float4*)(tt + 4) = tb[1];
    f16x4 rl, rh;
    #pragma unroll
    for (int j = 0; j < 4; ++j) {
      float cs = tt[2 * j], sn = tt[2 * j + 1];
      float x = ((const float*)&klo[it])[j];
      float y = ((const float*)&khi[it])[j];
      rl[j] = (_Float16)(x * cs - y * sn);
      rh[j] = (_Float16)(y * cs + x * sn);
    }
    *(f16x4*)(&ksm[row * KSTR + 4 * p])      = rl;
    *(f16x4*)(&ksm[row * KSTR + 4 * p + 32]) = rh;
  }

  // ================= V: 4x4 transpose -> vsm (b64 stores) =================
  #pragma unroll
  for (int it = 0; it < 2; ++it) {
    int kq = g + 4 * (it * 8 + wv);
    #pragma unroll
    for (int j = 0; j < 4; ++j) {
      f16x4 w;
      #pragma unroll
      for (int i = 0; i < 4; ++i) w[i] = (_Float16)(((const float*)&vr[it][i])[j]);
      *(f16x4*)(&vsm[(4 * c + j) * VSTR + 4 * kq]) = w;
    }
  }

  // ================= Q: rope via table -> B-fragments =================
  f16x8 qf0, qf1;
  {
    const float4* tb = (const float4*)(tbl + 2 * ((128 + qrow) * 32 + 8 * g));
    float tt[16];
    *(float4*)(tt)      = tb[0];
    *(float4*)(tt + 4)  = tb[1];
    *(float4*)(tt + 8)  = tb[2];
    *(float4*)(tt + 12) = tb[3];
    #pragma unroll
    for (int j = 0; j < 4; ++j) {
      float cs = tt[2 * j], sn = tt[2 * j + 1];
      float xa = ((const float*)&x0)[j], ya = ((const float*)&y0)[j];
      qf0[j]     = (_Float16)((xa * cs - ya * sn) * 0.125f);
      qf1[j]     = (_Float16)((ya * cs + xa * sn) * 0.125f);
      float cs2 = tt[8 + 2 * j], sn2 = tt[9 + 2 * j];
      float xb = ((const float*)&x1)[j], yb = ((const float*)&y1)[j];
      qf0[4 + j] = (_Float16)((xb * cs2 - yb * sn2) * 0.125f);
      qf1[4 + j] = (_Float16)((yb * cs2 + xb * sn2) * 0.125f);
    }
  }

  __syncthreads();

  // ---- QK^T (swapped: A=K -> S^T). key = 16*mt + 4*g + r, query = c ----
  f32x4 acc[16];
  #pragma unroll
  for (int mt = 0; mt < 16; ++mt) acc[mt] = (f32x4){0.f, 0.f, 0.f, 0.f};

  #pragma unroll
  for (int mt = 0; mt < 16; ++mt) {
    f16x8 kf0 = *(const f16x8*)(&ksm[(16 * mt + c) * KSTR + 8 * g]);
    f16x8 kf1 = *(const f16x8*)(&ksm[(16 * mt + c) * KSTR + 32 + 8 * g]);
    acc[mt] = __builtin_amdgcn_mfma_f32_16x16x32_f16(kf0, qf0, acc[mt], 0, 0, 0);
    acc[mt] = __builtin_amdgcn_mfma_f32_16x16x32_f16(kf1, qf1, acc[mt], 0, 0, 0);
  }

  // ---- masked softmax over keys ----
  const int qi   = qrow;
  const int kmin = (win == 0) ? 128 : 0;
  float m = -FLT_MAX;
  #pragma unroll
  for (int mt = 0; mt < 16; ++mt) {
    #pragma unroll
    for (int r = 0; r < 4; ++r) {
      int j = 16 * mt + 4 * g + r;
      bool ok = (j <= qi + 128) && (j >= kmin);
      float s = ok ? acc[mt][r] : -FLT_MAX;
      acc[mt][r] = s;
      m = fmaxf(m, s);
    }
  }
  m = fmaxf(m, __shfl_xor(m, 16));
  m = fmaxf(m, __shfl_xor(m, 32));

  float sm = 0.f;
  #pragma unroll
  for (int mt = 0; mt < 16; ++mt) {
    #pragma unroll
    for (int r = 0; r < 4; ++r) {
      float p = __expf(acc[mt][r] - m);
      acc[mt][r] = p;
      sm += p;
    }
  }
  sm += __shfl_xor(sm, 16);
  sm += __shfl_xor(sm, 32);
  const float rinv = 1.0f / sm;

  __syncthreads();  // all ksm reads done -> safe to alias with psm

  // ---- PV (R3 half-structure): O^T = V^T x P^T, A=V^T (vsm), B=P^T (psm) ----
  f32x4 oacc[4];
  #pragma unroll
  for (int nt = 0; nt < 4; ++nt) oacc[nt] = (f32x4){0.f, 0.f, 0.f, 0.f};

  _Float16* pw = psm + wv * 16 * PSTR;

  #pragma unroll
  for (int h = 0; h < 2; ++h) {
    if (h) {  // WAR: previous half's P reads must complete before overwrite
      asm volatile("s_waitcnt lgkmcnt(0)" ::: "memory");
      __builtin_amdgcn_sched_barrier(0);
    }
    #pragma unroll
    for (int mt8 = 0; mt8 < 8; ++mt8) {
      int mt = 8 * h + mt8;
      f16x4 pv4;
      #pragma unroll
      for (int r = 0; r < 4; ++r) pv4[r] = (_Float16)(acc[mt][r] * rinv);
      *(f16x4*)(&pw[c * PSTR + 16 * mt8 + 4 * g]) = pv4;
    }
    asm volatile("s_waitcnt lgkmcnt(0)" ::: "memory");
    __builtin_amdgcn_sched_barrier(0);

    #pragma unroll
    for (int ks = 0; ks < 4; ++ks) {
      f16x8 pf = *(const f16x8*)(&pw[c * PSTR + 32 * ks + 8 * g]);
      #pragma unroll
      for (int nt = 0; nt < 4; ++nt) {
        f16x8 vf = *(const f16x8*)(&vsm[(16 * nt + c) * VSTR + 128 * h + 32 * ks + 8 * g]);
        oacc[nt] = __builtin_amdgcn_mfma_f32_16x16x32_f16(vf, pf, oacc[nt], 0, 0, 0);
      }
    }
  }

  // ---- write O^T layout: lane (c,g) holds O[q=qrow][d=16nt+4g+r] -> float4 ----
  float* ob = out + ((size_t)bh * SEQ + (size_t)win * WIN + qrow) * DH;
  #pragma unroll
  for (int nt = 0; nt < 4; ++nt) {
    float4 o4 = {oacc[nt][0], oacc[nt][1], oacc[nt][2], oacc[nt][3]};
    *(float4*)(ob + 16 * nt + 4 * g) = o4;
  }
}

extern "C" void kernel_launch(void* const* d_in, const int* in_sizes, int n_in,
                              void* d_out, int out_size, void* d_ws, size_t ws_size,
                              hipStream_t stream) {
  const float* q = (const float*)d_in[0];
  const float* k = (const float*)d_in[1];
  const float* v = (const float*)d_in[2];
  float* out = (float*)d_out;
  float* tbl = (float*)d_ws;  // 256 pos x 32 freq x (cos,sin) = 64 KB

  rope_tbl_kernel<<<dim3(32), 256, 0, stream>>>(tbl);
  lattn_kernel<<<dim3(32 * 32), 512, 0, stream>>>(q, k, v, tbl, out);
}